// Round 2
// baseline (300.286 us; speedup 1.0000x reference)
//
#include <hip/hip_runtime.h>

// Negative-ELBO fused reduction.
// total = sum_w [0.5*x^2 - 0.5*((x-mu)/sigma)^2 - ln(sigma)]
//       + (0.5/sp^2) * sum_b (y - mu_p)^2
//       + BATCH * (ln(sp) + HALF_LOG_2PI)
// (HALF_LOG_2PI cancels between variational and prior terms.)

constexpr int BLOCKS  = 2048;
constexpr int THREADS = 256;
constexpr float LN2          = 0.6931471805599453f;
constexpr float HALF_LOG_2PI = 0.9189385332046727f;

__global__ __launch_bounds__(THREADS) void elbo_partial(
    const float* __restrict__ xw,   // noisy_weights
    const float* __restrict__ muw,  // mu_weights
    const float* __restrict__ sgw,  // sigma_weights
    const float* __restrict__ mup,  // mu_prediction
    const float* __restrict__ sp_ptr, // sigma_prediction (1 elem)
    const float* __restrict__ yt,   // y_true
    float* __restrict__ partial,    // [gridDim.x]
    int n4)
{
    const float4* x4 = (const float4*)xw;
    const float4* m4 = (const float4*)muw;
    const float4* s4 = (const float4*)sgw;
    const float4* p4 = (const float4*)mup;
    const float4* y4 = (const float4*)yt;

    float aw = 0.f;  // sum (x^2 - z^2)
    float al = 0.f;  // sum log2(sigma)
    float ab = 0.f;  // sum (y - mu_p)^2
    int idx    = blockIdx.x * blockDim.x + threadIdx.x;
    int stride = gridDim.x * blockDim.x;
    for (int i = idx; i < n4; i += stride) {
        float4 xv = x4[i];
        float4 mv = m4[i];
        float4 sv = s4[i];
        float4 pv = p4[i];
        float4 yv = y4[i];
#define COMP(c) {                                   \
        float dx = xv.c - mv.c;                     \
        float r  = __builtin_amdgcn_rcpf(sv.c);     \
        float z  = dx * r;                          \
        aw += xv.c * xv.c - z * z;                  \
        al += __log2f(sv.c);                        \
        float d  = yv.c - pv.c;                     \
        ab += d * d; }
        COMP(x) COMP(y) COMP(z) COMP(w)
#undef COMP
    }
    float sp = sp_ptr[0];
    float inv2sp2 = 0.5f * __builtin_amdgcn_rcpf(sp * sp);
    float v = 0.5f * aw - LN2 * al + inv2sp2 * ab;

    // wave-64 butterfly-down reduce
    for (int off = 32; off > 0; off >>= 1)
        v += __shfl_down(v, off);

    __shared__ float lds[THREADS / 64];
    int lane = threadIdx.x & 63;
    int wave = threadIdx.x >> 6;
    if (lane == 0) lds[wave] = v;
    __syncthreads();
    if (threadIdx.x == 0)
        partial[blockIdx.x] = lds[0] + lds[1] + lds[2] + lds[3];
}

__global__ __launch_bounds__(256) void elbo_final(
    const float* __restrict__ partial,
    const float* __restrict__ sp_ptr,
    float* __restrict__ out,
    int nblocks, float batch_f)
{
    float v = 0.f;
    for (int i = threadIdx.x; i < nblocks; i += 256)
        v += partial[i];
    for (int off = 32; off > 0; off >>= 1)
        v += __shfl_down(v, off);
    __shared__ float lds[4];
    int lane = threadIdx.x & 63;
    int wave = threadIdx.x >> 6;
    if (lane == 0) lds[wave] = v;
    __syncthreads();
    if (threadIdx.x == 0) {
        float sp = sp_ptr[0];
        float c  = batch_f * (logf(sp) + HALF_LOG_2PI);
        out[0] = lds[0] + lds[1] + lds[2] + lds[3] + c;
    }
}

extern "C" void kernel_launch(void* const* d_in, const int* in_sizes, int n_in,
                              void* d_out, int out_size, void* d_ws, size_t ws_size,
                              hipStream_t stream) {
    const float* xw  = (const float*)d_in[0];  // noisy_weights
    const float* muw = (const float*)d_in[1];  // mu_weights
    const float* sgw = (const float*)d_in[2];  // sigma_weights
    const float* mup = (const float*)d_in[3];  // mu_prediction
    const float* sp  = (const float*)d_in[4];  // sigma_prediction (scalar)
    const float* yt  = (const float*)d_in[5];  // y_true
    float* out     = (float*)d_out;
    float* partial = (float*)d_ws;

    int n  = in_sizes[0];   // N_WEIGHTS == BATCH
    int n4 = n / 4;

    elbo_partial<<<BLOCKS, THREADS, 0, stream>>>(xw, muw, sgw, mup, sp, yt,
                                                 partial, n4);
    elbo_final<<<1, 256, 0, stream>>>(partial, sp, out, BLOCKS,
                                      (float)in_sizes[5]);
}

// Round 4
// 297.180 us; speedup vs baseline: 1.0104x; 1.0104x over previous
//
#include <hip/hip_runtime.h>

// Negative-ELBO fused reduction.
// total = sum_w [0.5*x^2 - 0.5*((x-mu)/sigma)^2 - ln(sigma)]
//       + (0.5/sp^2) * sum_b (y - mu_p)^2
//       + BATCH * (ln(sp) + HALF_LOG_2PI)
// (HALF_LOG_2PI cancels between variational and prior terms.)
//
// R2: latency-bound fix — compile-time ITERS so all loads issue up front
// (VGPR 20 -> ~110, per-wave MLP 5 -> 20 float4 loads in flight).

constexpr int THREADS = 256;
constexpr int ITERS   = 4;               // float4 iterations per thread
constexpr float LN2          = 0.6931471805599453f;
constexpr float HALF_LOG_2PI = 0.9189385332046727f;

__global__ __launch_bounds__(THREADS, 4) void elbo_partial_fixed(
    const float* __restrict__ xw,
    const float* __restrict__ muw,
    const float* __restrict__ sgw,
    const float* __restrict__ mup,
    const float* __restrict__ sp_ptr,
    const float* __restrict__ yt,
    float* __restrict__ partial)
{
    const float4* x4 = (const float4*)xw;
    const float4* m4 = (const float4*)muw;
    const float4* s4 = (const float4*)sgw;
    const float4* p4 = (const float4*)mup;
    const float4* y4 = (const float4*)yt;

    const int base = blockIdx.x * (THREADS * ITERS) + threadIdx.x;

    float4 xv[ITERS], mv[ITERS], sv[ITERS], pv[ITERS], yv[ITERS];
#pragma unroll
    for (int it = 0; it < ITERS; ++it) {
        int i = base + it * THREADS;
        xv[it] = x4[i];
        mv[it] = m4[i];
        sv[it] = s4[i];
        pv[it] = p4[i];
        yv[it] = y4[i];
    }

    float aw = 0.f;  // sum (x^2 - z^2)
    float al = 0.f;  // sum log2(sigma)
    float ab = 0.f;  // sum (y - mu_p)^2
#pragma unroll
    for (int it = 0; it < ITERS; ++it) {
#define COMP(c) {                                        \
        float dx = xv[it].c - mv[it].c;                  \
        float r  = __builtin_amdgcn_rcpf(sv[it].c);      \
        float z  = dx * r;                               \
        aw += xv[it].c * xv[it].c - z * z;               \
        al += __log2f(sv[it].c);                         \
        float d  = yv[it].c - pv[it].c;                  \
        ab += d * d; }
        COMP(x) COMP(y) COMP(z) COMP(w)
#undef COMP
    }

    float sp = sp_ptr[0];
    float inv2sp2 = 0.5f * __builtin_amdgcn_rcpf(sp * sp);
    float v = 0.5f * aw - LN2 * al + inv2sp2 * ab;

    for (int off = 32; off > 0; off >>= 1)
        v += __shfl_down(v, off);

    __shared__ float lds[THREADS / 64];
    int lane = threadIdx.x & 63;
    int wave = threadIdx.x >> 6;
    if (lane == 0) lds[wave] = v;
    __syncthreads();
    if (threadIdx.x == 0)
        partial[blockIdx.x] = lds[0] + lds[1] + lds[2] + lds[3];
}

// Generic fallback (runtime trip count) in case sizes change.
__global__ __launch_bounds__(THREADS) void elbo_partial_generic(
    const float* __restrict__ xw,
    const float* __restrict__ muw,
    const float* __restrict__ sgw,
    const float* __restrict__ mup,
    const float* __restrict__ sp_ptr,
    const float* __restrict__ yt,
    float* __restrict__ partial,
    int n4)
{
    const float4* x4 = (const float4*)xw;
    const float4* m4 = (const float4*)muw;
    const float4* s4 = (const float4*)sgw;
    const float4* p4 = (const float4*)mup;
    const float4* y4 = (const float4*)yt;

    float aw = 0.f, al = 0.f, ab = 0.f;
    int idx    = blockIdx.x * blockDim.x + threadIdx.x;
    int stride = gridDim.x * blockDim.x;
    for (int i = idx; i < n4; i += stride) {
        float4 xv = x4[i], mv = m4[i], sv = s4[i], pv = p4[i], yv = y4[i];
#define COMP(c) {                                   \
        float dx = xv.c - mv.c;                     \
        float r  = __builtin_amdgcn_rcpf(sv.c);     \
        float z  = dx * r;                          \
        aw += xv.c * xv.c - z * z;                  \
        al += __log2f(sv.c);                        \
        float d  = yv.c - pv.c;                     \
        ab += d * d; }
        COMP(x) COMP(y) COMP(z) COMP(w)
#undef COMP
    }
    float sp = sp_ptr[0];
    float inv2sp2 = 0.5f * __builtin_amdgcn_rcpf(sp * sp);
    float v = 0.5f * aw - LN2 * al + inv2sp2 * ab;

    for (int off = 32; off > 0; off >>= 1)
        v += __shfl_down(v, off);

    __shared__ float lds[THREADS / 64];
    int lane = threadIdx.x & 63;
    int wave = threadIdx.x >> 6;
    if (lane == 0) lds[wave] = v;
    __syncthreads();
    if (threadIdx.x == 0)
        partial[blockIdx.x] = lds[0] + lds[1] + lds[2] + lds[3];
}

__global__ __launch_bounds__(256) void elbo_final(
    const float* __restrict__ partial,
    const float* __restrict__ sp_ptr,
    float* __restrict__ out,
    int nblocks, float batch_f)
{
    float v = 0.f;
    for (int i = threadIdx.x; i < nblocks; i += 256)
        v += partial[i];
    for (int off = 32; off > 0; off >>= 1)
        v += __shfl_down(v, off);
    __shared__ float lds[4];
    int lane = threadIdx.x & 63;
    int wave = threadIdx.x >> 6;
    if (lane == 0) lds[wave] = v;
    __syncthreads();
    if (threadIdx.x == 0) {
        float sp = sp_ptr[0];
        float c  = batch_f * (logf(sp) + HALF_LOG_2PI);
        out[0] = lds[0] + lds[1] + lds[2] + lds[3] + c;
    }
}

extern "C" void kernel_launch(void* const* d_in, const int* in_sizes, int n_in,
                              void* d_out, int out_size, void* d_ws, size_t ws_size,
                              hipStream_t stream) {
    const float* xw  = (const float*)d_in[0];  // noisy_weights
    const float* muw = (const float*)d_in[1];  // mu_weights
    const float* sgw = (const float*)d_in[2];  // sigma_weights
    const float* mup = (const float*)d_in[3];  // mu_prediction
    const float* sp  = (const float*)d_in[4];  // sigma_prediction (scalar)
    const float* yt  = (const float*)d_in[5];  // y_true
    float* out     = (float*)d_out;
    float* partial = (float*)d_ws;

    int n  = in_sizes[0];   // N_WEIGHTS == BATCH
    int n4 = n / 4;
    const int chunk = THREADS * ITERS;   // float4s per block

    int nblocks;
    if (n4 % chunk == 0) {
        nblocks = n4 / chunk;            // 4096 for n = 2^24
        elbo_partial_fixed<<<nblocks, THREADS, 0, stream>>>(
            xw, muw, sgw, mup, sp, yt, partial);
    } else {
        nblocks = 2048;
        elbo_partial_generic<<<nblocks, THREADS, 0, stream>>>(
            xw, muw, sgw, mup, sp, yt, partial, n4);
    }
    elbo_final<<<1, 256, 0, stream>>>(partial, sp, out, nblocks,
                                      (float)in_sizes[5]);
}

// Round 5
// 295.259 us; speedup vs baseline: 1.0170x; 1.0065x over previous
//
#include <hip/hip_runtime.h>

// Negative-ELBO fused reduction.
// total = sum_w [0.5*x^2 - 0.5*((x-mu)/sigma)^2 - ln(sigma)]
//       + (0.5/sp^2) * sum_b (y - mu_p)^2
//       + BATCH * (ln(sp) + HALF_LOG_2PI)
// (HALF_LOG_2PI cancels between variational and prior terms.)
//
// R4: (1) sched_barrier(0) after load cluster so the compiler cannot sink
// loads (R2's prefetch was silently undone, VGPR stayed 36); (2) grid split
// by term: weights blocks read 3 streams, prediction blocks read 2 streams
// (was 5 streams/wave), improving per-wave DRAM locality.

constexpr int THREADS = 256;
constexpr int WITERS  = 4;   // float4 per thread, weights path
constexpr int PITERS  = 8;   // float4 per thread, prediction path
constexpr float LN2          = 0.6931471805599453f;
constexpr float HALF_LOG_2PI = 0.9189385332046727f;

__device__ __forceinline__ float block_reduce(float v, float* lds4) {
    for (int off = 32; off > 0; off >>= 1)
        v += __shfl_down(v, off);
    int lane = threadIdx.x & 63;
    int wave = threadIdx.x >> 6;
    if (lane == 0) lds4[wave] = v;
    __syncthreads();
    return lds4[0] + lds4[1] + lds4[2] + lds4[3];
}

__global__ __launch_bounds__(THREADS, 4) void elbo_split(
    const float* __restrict__ xw,
    const float* __restrict__ muw,
    const float* __restrict__ sgw,
    const float* __restrict__ mup,
    const float* __restrict__ sp_ptr,
    const float* __restrict__ yt,
    float* __restrict__ partial,
    int wblocks)
{
    __shared__ float lds4[THREADS / 64];
    const int b = blockIdx.x;
    float v;

    if (b < wblocks) {
        // ---- weights term: 0.5*x^2 - 0.5*((x-mu)/sigma)^2 - ln(sigma) ----
        const float4* x4 = (const float4*)xw;
        const float4* m4 = (const float4*)muw;
        const float4* s4 = (const float4*)sgw;
        const int base = b * (THREADS * WITERS) + threadIdx.x;

        float4 xv[WITERS], mv[WITERS], sv[WITERS];
#pragma unroll
        for (int it = 0; it < WITERS; ++it) {
            int i = base + it * THREADS;
            xv[it] = x4[i];
            mv[it] = m4[i];
            sv[it] = s4[i];
        }
        __builtin_amdgcn_sched_barrier(0);   // loads may not sink past here

        float aw = 0.f;  // sum (x^2 - z^2)
        float al = 0.f;  // sum log2(sigma)
#pragma unroll
        for (int it = 0; it < WITERS; ++it) {
#define WCOMP(c) {                                       \
            float dx = xv[it].c - mv[it].c;              \
            float r  = __builtin_amdgcn_rcpf(sv[it].c);  \
            float z  = dx * r;                           \
            aw += xv[it].c * xv[it].c - z * z;           \
            al += __log2f(sv[it].c); }
            WCOMP(x) WCOMP(y) WCOMP(z) WCOMP(w)
#undef WCOMP
        }
        v = 0.5f * aw - LN2 * al;
    } else {
        // ---- likelihood term: (0.5/sp^2) * (y - mu_p)^2 ----
        const float4* p4 = (const float4*)mup;
        const float4* y4 = (const float4*)yt;
        const int base = (b - wblocks) * (THREADS * PITERS) + threadIdx.x;

        float4 pv[PITERS], yv[PITERS];
#pragma unroll
        for (int it = 0; it < PITERS; ++it) {
            int i = base + it * THREADS;
            pv[it] = p4[i];
            yv[it] = y4[i];
        }
        __builtin_amdgcn_sched_barrier(0);

        float ab = 0.f;
#pragma unroll
        for (int it = 0; it < PITERS; ++it) {
#define PCOMP(c) {                                       \
            float d = yv[it].c - pv[it].c;               \
            ab += d * d; }
            PCOMP(x) PCOMP(y) PCOMP(z) PCOMP(w)
#undef PCOMP
        }
        float sp = sp_ptr[0];
        v = 0.5f * __builtin_amdgcn_rcpf(sp * sp) * ab;
    }

    v = block_reduce(v, lds4);
    if (threadIdx.x == 0)
        partial[b] = v;
}

// Generic fallback (runtime sizes / non-divisible shapes).
__global__ __launch_bounds__(THREADS) void elbo_partial_generic(
    const float* __restrict__ xw,
    const float* __restrict__ muw,
    const float* __restrict__ sgw,
    const float* __restrict__ mup,
    const float* __restrict__ sp_ptr,
    const float* __restrict__ yt,
    float* __restrict__ partial,
    int n4w, int n4p)
{
    const float4* x4 = (const float4*)xw;
    const float4* m4 = (const float4*)muw;
    const float4* s4 = (const float4*)sgw;
    const float4* p4 = (const float4*)mup;
    const float4* y4 = (const float4*)yt;

    float aw = 0.f, al = 0.f, ab = 0.f;
    int idx    = blockIdx.x * blockDim.x + threadIdx.x;
    int stride = gridDim.x * blockDim.x;
    for (int i = idx; i < n4w; i += stride) {
        float4 xv = x4[i], mv = m4[i], sv = s4[i];
#define WCOMP(c) {                                  \
        float dx = xv.c - mv.c;                     \
        float r  = __builtin_amdgcn_rcpf(sv.c);     \
        float z  = dx * r;                          \
        aw += xv.c * xv.c - z * z;                  \
        al += __log2f(sv.c); }
        WCOMP(x) WCOMP(y) WCOMP(z) WCOMP(w)
#undef WCOMP
    }
    for (int i = idx; i < n4p; i += stride) {
        float4 pv = p4[i], yv = y4[i];
#define PCOMP(c) {                                  \
        float d = yv.c - pv.c;                      \
        ab += d * d; }
        PCOMP(x) PCOMP(y) PCOMP(z) PCOMP(w)
#undef PCOMP
    }
    float sp = sp_ptr[0];
    float v = 0.5f * aw - LN2 * al
            + 0.5f * __builtin_amdgcn_rcpf(sp * sp) * ab;

    __shared__ float lds4[THREADS / 64];
    v = block_reduce(v, lds4);
    if (threadIdx.x == 0)
        partial[blockIdx.x] = v;
}

__global__ __launch_bounds__(256) void elbo_final(
    const float* __restrict__ partial,
    const float* __restrict__ sp_ptr,
    float* __restrict__ out,
    int nblocks, float batch_f)
{
    float v = 0.f;
    for (int i = threadIdx.x; i < nblocks; i += 256)
        v += partial[i];
    for (int off = 32; off > 0; off >>= 1)
        v += __shfl_down(v, off);
    __shared__ float lds[4];
    int lane = threadIdx.x & 63;
    int wave = threadIdx.x >> 6;
    if (lane == 0) lds[wave] = v;
    __syncthreads();
    if (threadIdx.x == 0) {
        float sp = sp_ptr[0];
        float c  = batch_f * (logf(sp) + HALF_LOG_2PI);
        out[0] = lds[0] + lds[1] + lds[2] + lds[3] + c;
    }
}

extern "C" void kernel_launch(void* const* d_in, const int* in_sizes, int n_in,
                              void* d_out, int out_size, void* d_ws, size_t ws_size,
                              hipStream_t stream) {
    const float* xw  = (const float*)d_in[0];  // noisy_weights
    const float* muw = (const float*)d_in[1];  // mu_weights
    const float* sgw = (const float*)d_in[2];  // sigma_weights
    const float* mup = (const float*)d_in[3];  // mu_prediction
    const float* sp  = (const float*)d_in[4];  // sigma_prediction (scalar)
    const float* yt  = (const float*)d_in[5];  // y_true
    float* out     = (float*)d_out;
    float* partial = (float*)d_ws;

    int nw  = in_sizes[0];          // N_WEIGHTS
    int np  = in_sizes[5];          // BATCH
    int n4w = nw / 4;
    int n4p = np / 4;
    const int wchunk = THREADS * WITERS;   // float4s per weights block
    const int pchunk = THREADS * PITERS;   // float4s per pred block

    if ((nw % 4 == 0) && (np % 4 == 0) &&
        (n4w % wchunk == 0) && (n4p % pchunk == 0)) {
        int wblocks = n4w / wchunk;        // 4096 for 2^24
        int pblocks = n4p / pchunk;        // 2048 for 2^24
        int nblocks = wblocks + pblocks;
        elbo_split<<<nblocks, THREADS, 0, stream>>>(
            xw, muw, sgw, mup, sp, yt, partial, wblocks);
        elbo_final<<<1, 256, 0, stream>>>(partial, sp, out, nblocks,
                                          (float)np);
    } else {
        int nblocks = 2048;
        elbo_partial_generic<<<nblocks, THREADS, 0, stream>>>(
            xw, muw, sgw, mup, sp, yt, partial, n4w, n4p);
        elbo_final<<<1, 256, 0, stream>>>(partial, sp, out, nblocks,
                                          (float)np);
    }
}